// Round 18
// baseline (126.581 us; speedup 1.0000x reference)
//
#include <hip/hip_runtime.h>
#include <math.h>

#define VOCABN 100000
#define EMBD 300
#define HID 128
#define NQ 32
#define NTOP 10

#define NCHS 19             // chunks scored, 16 k each (k 0..303, tail zero-padded)
#define CMIN 3
#define NBLK_AC 2048
#define RANGE 49            // 2048*49 = 100352 >= VOCABN; <=64 -> single ballot iter
#define RANGE_PAD 64
#define GRID_F ((VOCABN + 31) / 32)   // 3125 dense tiles (fallback)
#define HB 512              // histogram blocks
#define WARMB 16            // L3-warming blocks appended to k_hist
#define EW1_F4 ((3 * EMBD * HID) / 4)   // 28800
#define EW2_F4 ((HID * EMBD) / 4)       // 9600

typedef __attribute__((ext_vector_type(8))) short bf16x8;
typedef __attribute__((ext_vector_type(4))) float f32x4;
typedef __attribute__((ext_vector_type(16))) float f32x16;
typedef __attribute__((ext_vector_type(4))) unsigned int u32x4;
typedef __attribute__((ext_vector_type(4))) int i32x4;

__device__ __forceinline__ void split8(const f32x4 a, const f32x4 b,
                                       u32x4* hi, u32x4* lo) {
    float ef[8] = {a.x, a.y, a.z, a.w, b.x, b.y, b.z, b.w};
    unsigned int hw[8], lw[8];
#pragma unroll
    for (int j = 0; j < 8; ++j) {
        unsigned int u = __float_as_uint(ef[j]);
        hw[j] = u >> 16;
        float r = __uint_as_float(u & 0xffff0000u);
        lw[j] = __float_as_uint(ef[j] - r) >> 16;
    }
    *hi = (u32x4){hw[0] | (hw[1] << 16), hw[2] | (hw[3] << 16),
                  hw[4] | (hw[5] << 16), hw[6] | (hw[7] << 16)};
    *lo = (u32x4){lw[0] | (lw[1] << 16), lw[2] | (lw[3] << 16),
                  lw[4] | (lw[5] << 16), lw[6] | (lw[7] << 16)};
}

__device__ __forceinline__ bool tbetter(float w1, int i1, float w2, int i2) {
    return w1 > w2 || (w1 == w2 && i1 < i2);
}

__device__ __forceinline__ void lds_insert(float* mw, int* mid, int t, float w, int id) {
    const int b = t * NTOP;
    if (!tbetter(w, id, mw[b + NTOP - 1], mid[b + NTOP - 1])) return;
    int p = NTOP - 1;
    while (p > 0 && tbetter(w, id, mw[b + p - 1], mid[b + p - 1])) {
        mw[b + p] = mw[b + p - 1]; mid[b + p] = mid[b + p - 1]; --p;
    }
    mw[b + p] = w; mid[b + p] = id;
}

// ---------- depth-2 scorer macros (r11 variant: 72 VGPR, no spill) ----------
#define LOADC_CORE(NN, S)                                                    \
    { int nn_ = (NN);                                                        \
      if (nn_ < NCHS) {                                                      \
          int k0_ = nn_ * 16 + khalf * 8;                                    \
          e0[S] = (k0_ + 4 <= EMBD) ? *(const f32x4*)(ebase + k0_) : zf4;    \
          e1[S] = (k0_ + 8 <= EMBD) ? *(const f32x4*)(ebase + k0_ + 4) : zf4;\
          _Pragma("unroll")                                                  \
          for (int t_ = 0; t_ < 4; ++t_) {                                   \
              long fo_ = ((long)(nn_ * 4 + t_) * 64 + lane) * 8;             \
              wh[S][t_] = *(const u32x4*)&wfH[fo_];                          \
              wl[S][t_] = *(const u32x4*)&wfL[fo_];                          \
          } } }

#define COMP_CORE(CC, S)                                                     \
    { if ((CC) < NCHS) {                                                     \
          union { bf16x8 v; u32x4 u; } eh_, el_;                             \
          split8(e0[S], e1[S], &eh_.u, &el_.u);                              \
          _Pragma("unroll")                                                  \
          for (int t_ = 0; t_ < 4; ++t_) {                                   \
              union { bf16x8 v; u32x4 u; } bh_, bl_;                         \
              bh_.u = wh[S][t_]; bl_.u = wl[S][t_];                          \
              acc[t_] = __builtin_amdgcn_mfma_f32_32x32x16_bf16(eh_.v, bh_.v, acc[t_], 0, 0, 0); \
              acc[t_] = __builtin_amdgcn_mfma_f32_32x32x16_bf16(eh_.v, bl_.v, acc[t_], 0, 0, 0); \
              acc[t_] = __builtin_amdgcn_mfma_f32_32x32x16_bf16(el_.v, bh_.v, acc[t_], 0, 0, 0); \
          } } }

// scoring body for one 32-row batch: fills pv[0..31] with W2-reduced row sums
#define SCORE_BATCH_BODY                                                     \
    {                                                                        \
        f32x16 acc[4];                                                       \
        _Pragma("unroll")                                                    \
        for (int t_ = 0; t_ < 4; ++t_)                                       \
            _Pragma("unroll")                                                \
            for (int r_ = 0; r_ < 16; ++r_) acc[t_][r_] = 0.f;               \
        f32x4 e0[2], e1[2];                                                  \
        u32x4 wh[2][4], wl[2][4];                                            \
        const f32x4 zf4 = (f32x4){0.f, 0.f, 0.f, 0.f};                       \
        LOADC_CORE(0, 0) LOADC_CORE(1, 1)                                    \
        for (int g_ = 0; g_ < 10; ++g_) {                                    \
            const int c_ = g_ * 2;                                           \
            COMP_CORE(c_ + 0, 0) LOADC_CORE(c_ + 2, 0)                       \
            COMP_CORE(c_ + 1, 1) LOADC_CORE(c_ + 3, 1)                       \
        }                                                                    \
        float pr[16];                                                        \
        _Pragma("unroll")                                                    \
        for (int r_ = 0; r_ < 16; ++r_) {                                    \
            float s_ = 0.f;                                                  \
            _Pragma("unroll")                                                \
            for (int t_ = 0; t_ < 4; ++t_) {                                 \
                float h_ = fmaxf(acc[t_][r_] + qv[t_], 0.f);                 \
                s_ += h_ * w2v[t_];                                          \
            }                                                                \
            s_ += __shfl_xor(s_, 1); s_ += __shfl_xor(s_, 2);                \
            s_ += __shfl_xor(s_, 4); s_ += __shfl_xor(s_, 8);                \
            s_ += __shfl_xor(s_, 16);                                        \
            pr[r_] = s_;                                                     \
        }                                                                    \
        if (lrow == 0) {                                                     \
            _Pragma("unroll")                                                \
            for (int r_ = 0; r_ < 16; ++r_)                                  \
                pv[(r_ & 3) + 8 * (r_ >> 2) + 4 * khalf] = pr[r_];           \
        }                                                                    \
        asm volatile("s_waitcnt lgkmcnt(0)" ::: "memory");                   \
        __builtin_amdgcn_sched_barrier(0);                                   \
    }

// full-tile scorer used only in the rare fallback (proven r12)
__device__ void score_tiles(int gw, int nwaves, const float* __restrict__ emb,
                            const unsigned short* __restrict__ wfH,
                            const unsigned short* __restrict__ wfL,
                            const float* __restrict__ qcbp,
                            const float* __restrict__ w2p, float b2,
                            const int* __restrict__ counts, int ncand,
                            float* __restrict__ taw, int* __restrict__ tai,
                            float* pv) {
    const int lane = threadIdx.x & 63;
    const int lrow = lane & 31;
    const int khalf = lane >> 5;
    const int ntile = (ncand + 31) >> 5;

    float qv[4], w2v[4];
#pragma unroll
    for (int t = 0; t < 4; ++t) {
        qv[t] = qcbp[t * 32 + lrow];
        w2v[t] = w2p[t * 32 + lrow];
    }

    for (int tile = gw; tile < ntile; tile += nwaves) {
        const int base = tile * 32;
        int ri = base + lrow;
        int rc = ri < ncand ? ri : ncand - 1;
        const float* ebase = emb + (long)rc * EMBD;

        SCORE_BATCH_BODY

        int gidx = base + lrow;
        float w = -1.f; int id = 0x7fffffff;
        if (gidx < ncand) {
            id = gidx;
            w = (float)counts[gidx] / (1.f + expf(-(pv[lrow] + b2)));
        }
        for (int r = 0; r < NTOP; ++r) {
            float bw = w; int bid = id;
#pragma unroll
            for (int m = 1; m < 32; m <<= 1) {
                float ow = __shfl_xor(bw, m); int oid = __shfl_xor(bid, m);
                if (ow > bw || (ow == bw && oid < bid)) { bw = ow; bid = oid; }
            }
            if (w == bw && id == bid) w = -2.f;
            if (lane == r) { taw[tile * NTOP + r] = bw; tai[tile * NTOP + r] = bid; }
        }
    }
}

// ---------- k_init: zero counts | qctx | qcb | W fragment table ----------
__global__ __launch_bounds__(64) void k_init(const int* __restrict__ qterms,
                                             const float* __restrict__ emb,
                                             const float* __restrict__ sW1,
                                             const float* __restrict__ sb1,
                                             char* __restrict__ ws) {
    int* counts = (int*)ws;
    float* qctx = (float*)(ws + 400064);
    float* qcb  = (float*)(ws + 401280);
    unsigned short* wfH = (unsigned short*)(ws + 401920);
    unsigned short* wfL = (unsigned short*)(ws + 483840);
    const int t = threadIdx.x;
    const int b = blockIdx.x;

    for (int i = b * 64 + t; i < VOCABN; i += 512 * 64) counts[i] = 0;

    if (b < 4) {                       // qctx: 75 dims per block
        __shared__ int qid[NQ];
        if (t < NQ) qid[t] = qterms[t];
        __syncthreads();
        for (int d = t; d < 75; d += 64) {
            int dim = b * 75 + d;
            float s = 0.f;
            for (int q = 0; q < NQ; ++q) s += emb[(long)qid[q] * EMBD + dim];
            qctx[dim] = s * (1.0f / NQ);
        }
        return;
    }
    if (b == 4) {                      // qcb = sb1 + qctx . W1b (local qc recompute)
        __shared__ int qid[NQ];
        __shared__ float qc[EMBD];
        if (t < NQ) qid[t] = qterms[t];
        __syncthreads();
        for (int d = t; d < EMBD; d += 64) {
            float s = 0.f;
            for (int q = 0; q < NQ; ++q) s += emb[(long)qid[q] * EMBD + d];
            qc[d] = s * (1.0f / NQ);
        }
        __syncthreads();
        float a0 = 0.f, a1 = 0.f;
        for (int k = 0; k < EMBD; ++k) {
            float q = qc[k];
            a0 += q * sW1[(long)(EMBD + k) * HID + t];
            a1 += q * sW1[(long)(EMBD + k) * HID + t + 64];
        }
        qcb[t] = a0 + sb1[t];
        qcb[t + 64] = a1 + sb1[t + 64];
        return;
    }
    if (b < 85) {                      // W fragment table: 5120 builders
        int i = (b - 5) * 64 + t;
        int c = i >> 8;
        int rest = i & 255;
        int tile = rest >> 6;
        int l = rest & 63;
        int col = tile * 32 + (l & 31);
        int kbase = c * 16 + (l >> 5) * 8;
        unsigned int hw[8], lw[8];
#pragma unroll
        for (int j = 0; j < 8; ++j) {
            int k = kbase + j;
            unsigned int hi = 0, lo = 0;
            if (k < EMBD) {
                float f = sW1[(long)k * HID + col];
                unsigned int u = __float_as_uint(f);
                hi = u >> 16;
                float r = __uint_as_float(u & 0xffff0000u);
                lo = __float_as_uint(f - r) >> 16;
            }
            hw[j] = hi; lw[j] = lo;
        }
        long fo = ((long)(c * 4 + tile) * 64 + l) * 8;
        *(u32x4*)&wfH[fo] = (u32x4){hw[0] | (hw[1] << 16), hw[2] | (hw[3] << 16),
                                    hw[4] | (hw[5] << 16), hw[6] | (hw[7] << 16)};
        *(u32x4*)&wfL[fo] = (u32x4){lw[0] | (lw[1] << 16), lw[2] | (lw[3] << 16),
                                    lw[4] | (lw[5] << 16), lw[6] | (lw[7] << 16)};
    }
}

// ---------- k_hist: histogram + L3 warm of expansion-MLP weights ----------
__global__ __launch_bounds__(256) void k_hist(const int* __restrict__ fdocs, int n,
                                              int* __restrict__ counts,
                                              const float* __restrict__ eW1,
                                              const float* __restrict__ eW2) {
    const int b = blockIdx.x;
    const int t = threadIdx.x;
    if (b >= HB) {
        // warm blocks: stream eW1/eW2 through L2/L3 so k_mergefinal hits warm lines
        int wt = (b - HB) * 256 + t;               // 0..4095
        f32x4 s4 = (f32x4){0.f, 0.f, 0.f, 0.f};
        for (int i = wt; i < EW1_F4; i += WARMB * 256) s4 += ((const f32x4*)eW1)[i];
        for (int i = wt; i < EW2_F4; i += WARMB * 256) s4 += ((const f32x4*)eW2)[i];
        float s = s4.x + s4.y + s4.z + s4.w;
        asm volatile("" :: "v"(s));                // keep loads alive (no DCE)
        return;
    }
    for (int i = b * 256 + t; i < n; i += HB * 256)
        atomicAdd(&counts[fdocs[i]], 1);
}

// ---------- k_scoreAC: 49-row range compact + <=2 batch MFMA score + wave top-10 ----------
__global__ __launch_bounds__(64) void k_scoreAC(
        const float* __restrict__ emb,
        const unsigned short* __restrict__ wfH,
        const unsigned short* __restrict__ wfL,
        const float* __restrict__ qcb,
        const float* __restrict__ sW2,
        const float* __restrict__ sb2,
        const int* __restrict__ counts,
        float* __restrict__ taw, int* __restrict__ tai) {
    const int lane = threadIdx.x;
    const int blk = blockIdx.x;
    const int lrow = lane & 31;
    const int khalf = lane >> 5;
    const int base0 = blk * RANGE;

    __shared__ int   cl_id[RANGE_PAD];
    __shared__ int   cl_cnt[RANGE_PAD];
    __shared__ float allw[RANGE_PAD];
    __shared__ float pv[32];

    // ---- single-iteration ballot compaction (RANGE <= 64, uniform trip) ----
    int v = base0 + lane;
    int c = (lane < RANGE && v < VOCABN) ? counts[v] : 0;
    bool pred = (c >= CMIN);
    unsigned long long m = __ballot(pred);
    if (pred) {
        int pos = __popcll(m & ((1ull << lane) - 1ull));
        cl_id[pos] = v; cl_cnt[pos] = c;
    }
    const int ncl = __popcll(m);
    __syncthreads();

    if (ncl == 0) {
        if (lane < NTOP) { taw[blk * NTOP + lane] = -1.f; tai[blk * NTOP + lane] = 0x7fffffff; }
        return;
    }

    float qv[4], w2v[4];
#pragma unroll
    for (int t = 0; t < 4; ++t) {
        qv[t] = qcb[t * 32 + lrow];
        w2v[t] = sW2[t * 32 + lrow];
    }
    const float b2 = sb2[0];

    // ---- up to 2 batches of 32 candidates ----
    const int nb = (ncl + 31) >> 5;
    for (int bt = 0; bt < nb; ++bt) {
        int idx = bt * 32 + lrow;
        bool val = idx < ncl;
        int vrow = val ? cl_id[idx] : cl_id[0];
        const float* ebase = emb + (long)vrow * EMBD;

        SCORE_BATCH_BODY

        float w = -1.f;
        if (val) w = (float)cl_cnt[idx] / (1.f + expf(-(pv[lrow] + b2)));
        allw[bt * 32 + lrow] = w;   // both lane halves write identical value
        __syncthreads();
    }

    // ---- wave top-10 over allw[0..ncl) with knockout ----
    for (int r = 0; r < NTOP; ++r) {
        float bw = -1.f; int bid = 0x7fffffff; int bslot = -1;
        if (lane < ncl) { bw = allw[lane]; bid = cl_id[lane]; bslot = lane; }
#pragma unroll
        for (int mm = 1; mm < 64; mm <<= 1) {
            float ow = __shfl_xor(bw, mm);
            int oid = __shfl_xor(bid, mm);
            int osl = __shfl_xor(bslot, mm);
            if (ow > bw || (ow == bw && oid < bid)) { bw = ow; bid = oid; bslot = osl; }
        }
        if (lane == 0 && bslot >= 0) allw[bslot] = -2.f;
        if (lane == r) { taw[blk * NTOP + r] = bw; tai[blk * NTOP + r] = bid; }
        __syncthreads();
    }
}

// ---------- k_mergefinal: prefetch weights -> merge + flag -> MLP (| rare fallback) ----------
__global__ __launch_bounds__(512) void k_mergefinal(
        const float* __restrict__ taw, const int* __restrict__ tai,
        const float* __restrict__ qctx, const float* __restrict__ emb,
        const unsigned short* __restrict__ wfH, const unsigned short* __restrict__ wfL,
        const float* __restrict__ qcb, const float* __restrict__ sW2,
        const float* __restrict__ sb2, const int* __restrict__ counts,
        const float* __restrict__ eW1, const float* __restrict__ eb1,
        const float* __restrict__ eW2, const float* __restrict__ eb2,
        float* __restrict__ tbw, int* __restrict__ tbi,
        float* __restrict__ out) {
    __shared__ float mw[512 * NTOP];
    __shared__ int   mid[512 * NTOP];
    __shared__ float pvs[8][32];
    __shared__ int   top_id[NTOP];
    __shared__ float qc[EMBD], em[EMBD], hbuf[HID];
    const int t = threadIdx.x;

    // ---- phase 0: streaming prefetch of MLP weights (L3-warm from k_hist ->
    // fills this XCD's L2 at max memory-level parallelism; sink kept alive) ----
    {
        f32x4 s4 = (f32x4){0.f, 0.f, 0.f, 0.f};
        for (int i = t; i < EW1_F4; i += 512) s4 += ((const f32x4*)eW1)[i];
        for (int i = t; i < EW2_F4; i += 512) s4 += ((const f32x4*)eW2)[i];
        float s = s4.x + s4.y + s4.z + s4.w;
        asm volatile("" :: "v"(s));
    }

    // ---- merge A candidates (2048 blocks x 10), float4-vectorized scan ----
#pragma unroll
    for (int n = 0; n < NTOP; ++n) { mw[t * NTOP + n] = -1.f; mid[t * NTOP + n] = 0x7fffffff; }
    for (int i4 = t; i4 < (NBLK_AC * NTOP) / 4; i4 += 512) {
        f32x4 w4 = ((const f32x4*)taw)[i4];
        i32x4 id4 = ((const i32x4*)tai)[i4];
        lds_insert(mw, mid, t, w4.x, id4.x);
        lds_insert(mw, mid, t, w4.y, id4.y);
        lds_insert(mw, mid, t, w4.z, id4.z);
        lds_insert(mw, mid, t, w4.w, id4.w);
    }
    for (int s = 256; s > 0; s >>= 1) {
        __syncthreads();
        if (t < s) {
            const int ta = t * NTOP, tb = (t + s) * NTOP;
            float ow[NTOP]; int oid[NTOP];
            int i = 0, j = 0;
#pragma unroll
            for (int n = 0; n < NTOP; ++n) {
                float wa = mw[ta + i]; int ia = mid[ta + i];
                float wb = mw[tb + j]; int ib = mid[tb + j];
                if (tbetter(wa, ia, wb, ib)) { ow[n] = wa; oid[n] = ia; ++i; }
                else                         { ow[n] = wb; oid[n] = ib; ++j; }
            }
#pragma unroll
            for (int n = 0; n < NTOP; ++n) { mw[ta + n] = ow[n]; mid[ta + n] = oid[n]; }
        }
    }
    __syncthreads();

    // exactness flag: excluded rows (count<=2) have weight = count*sigmoid < 2
    const bool flag = (mw[NTOP - 1] >= 2.0f);

    if (!flag) {
        // rare path: dense rescore of the full vocab by this block's 8 waves
        score_tiles(t >> 6, 8, emb, wfH, wfL, qcb, sW2, sb2[0],
                    counts, VOCABN, tbw, tbi, pvs[t >> 6]);
        __syncthreads();
#pragma unroll
        for (int n = 0; n < NTOP; ++n) { mw[t * NTOP + n] = -1.f; mid[t * NTOP + n] = 0x7fffffff; }
        for (int i = t; i < GRID_F * NTOP; i += 512)
            lds_insert(mw, mid, t, tbw[i], tbi[i]);
        for (int s = 256; s > 0; s >>= 1) {
            __syncthreads();
            if (t < s) {
                const int ta = t * NTOP, tb = (t + s) * NTOP;
                float ow[NTOP]; int oid[NTOP];
                int i = 0, j = 0;
#pragma unroll
                for (int n = 0; n < NTOP; ++n) {
                    float wa = mw[ta + i]; int ia = mid[ta + i];
                    float wb = mw[tb + j]; int ib = mid[tb + j];
                    if (tbetter(wa, ia, wb, ib)) { ow[n] = wa; oid[n] = ia; ++i; }
                    else                         { ow[n] = wb; oid[n] = ib; ++j; }
                }
#pragma unroll
                for (int n = 0; n < NTOP; ++n) { mw[ta + n] = ow[n]; mid[ta + n] = oid[n]; }
            }
        }
        __syncthreads();
    }

    if (t < NTOP) {
        top_id[t] = mid[t];
        out[EMBD + t] = (float)mid[t];
        out[EMBD + NTOP + t] = mw[t];
    }
    __syncthreads();

    for (int i = t; i < EMBD; i += 512) {
        float s = 0.f;
        for (int n = 0; n < NTOP; ++n) {
            long rid = top_id[n];
            if (rid > VOCABN - 1) rid = VOCABN - 1;   // sentinel clamp
            s += emb[rid * EMBD + i];
        }
        em[i] = s * (1.0f / NTOP);
        qc[i] = qctx[i];
    }
    __syncthreads();

    {   // h = relu(feat . eW1 + eb1); 4 threads per col, K split 75 (proven r12)
        int col = t >> 2, ks = t & 3;
        float a = 0.f;
        int k0 = ks * 75, k1 = k0 + 75;
        for (int k = k0; k < k1; ++k) {
            float q = qc[k], e = em[k];
            a += q * eW1[(long)k * HID + col];
            a += e * eW1[(long)(EMBD + k) * HID + col];
            a += (q * e) * eW1[(long)(2 * EMBD + k) * HID + col];
        }
        a += __shfl_xor(a, 1);
        a += __shfl_xor(a, 2);
        if (ks == 0) hbuf[col] = fmaxf(a + eb1[col], 0.f);
    }
    __syncthreads();

    for (int i = t; i < EMBD; i += 512) {
        float a = eb2[i];
        for (int j = 0; j < HID; ++j) a += hbuf[j] * eW2[(long)j * EMBD + i];
        out[i] = a;
    }
}

extern "C" void kernel_launch(void* const* d_in, const int* in_sizes, int n_in,
                              void* d_out, int out_size, void* d_ws, size_t ws_size,
                              hipStream_t stream) {
    const int* qterms  = (const int*)d_in[0];
    const int* fdocs   = (const int*)d_in[1];
    const float* emb   = (const float*)d_in[3];
    const float* sW1   = (const float*)d_in[4];
    const float* sb1   = (const float*)d_in[5];
    const float* sW2   = (const float*)d_in[6];
    const float* sb2   = (const float*)d_in[7];
    const float* eW1   = (const float*)d_in[8];
    const float* eb1   = (const float*)d_in[9];
    const float* eW2   = (const float*)d_in[10];
    const float* eb2   = (const float*)d_in[11];
    char* ws = (char*)d_ws;
    float* out = (float*)d_out;

    int*   counts = (int*)ws;                               // 400000
    float* qctx   = (float*)(ws + 400064);                  // 1200
    float* qcb    = (float*)(ws + 401280);                  // 512
    unsigned short* wfH = (unsigned short*)(ws + 401920);   // 81920
    unsigned short* wfL = (unsigned short*)(ws + 483840);   // 81920
    float* taw    = (float*)(ws + 565760);                  // 2048*10*4 = 81920
    int*   tai    = (int*)(ws + 647680);                    // 81920
    float* tbw    = (float*)(ws + 729600);                  // 125000
    int*   tbi    = (int*)(ws + 854600);                    // 125000 -> 979600 total

    int nflat = in_sizes[1];

    k_init<<<512, 64, 0, stream>>>(qterms, emb, sW1, sb1, ws);
    k_hist<<<HB + WARMB, 256, 0, stream>>>(fdocs, nflat, counts, eW1, eW2);
    k_scoreAC<<<NBLK_AC, 64, 0, stream>>>(emb, wfH, wfL, qcb, sW2, sb2, counts, taw, tai);
    k_mergefinal<<<1, 512, 0, stream>>>(taw, tai, qctx, emb, wfH, wfL, qcb, sW2, sb2,
                                        counts, eW1, eb1, eW2, eb2, tbw, tbi, out);
}

// Round 19
// 84.295 us; speedup vs baseline: 1.5016x; 1.5016x over previous
//
#include <hip/hip_runtime.h>
#include <math.h>

#define VOCABN 100000
#define EMBD 300
#define HID 128
#define NQ 32
#define NTOP 10

#define NCHS 19             // chunks scored, 16 k each (k 0..303, tail zero-padded)
#define CMIN 3
#define NBLK_AC 1024
#define RANGE 98            // 1024*98 = 100352 >= VOCABN; 2 uniform ballot iters
#define RANGE_PAD 128
#define HB 512              // histogram blocks in k_histplus
#define KSLC 57             // 16*57 = 912 >= 900 k-slice per k_mh block

typedef __attribute__((ext_vector_type(8))) short bf16x8;
typedef __attribute__((ext_vector_type(4))) float f32x4;
typedef __attribute__((ext_vector_type(16))) float f32x16;
typedef __attribute__((ext_vector_type(4))) unsigned int u32x4;
typedef unsigned long long u64;

// ws layout
#define WS_HACC   400000
#define WS_QCTX   400512
#define WS_QCB    401712
#define WS_WFH    402224
#define WS_WFL    484144
#define WS_TPACK  566064   // 1024*10*8 = 81920 -> end 647984

__device__ __forceinline__ void split8(const f32x4 a, const f32x4 b,
                                       u32x4* hi, u32x4* lo) {
    float ef[8] = {a.x, a.y, a.z, a.w, b.x, b.y, b.z, b.w};
    unsigned int hw[8], lw[8];
#pragma unroll
    for (int j = 0; j < 8; ++j) {
        unsigned int u = __float_as_uint(ef[j]);
        hw[j] = u >> 16;
        float r = __uint_as_float(u & 0xffff0000u);
        lw[j] = __float_as_uint(ef[j] - r) >> 16;
    }
    *hi = (u32x4){hw[0] | (hw[1] << 16), hw[2] | (hw[3] << 16),
                  hw[4] | (hw[5] << 16), hw[6] | (hw[7] << 16)};
    *lo = (u32x4){lw[0] | (lw[1] << 16), lw[2] | (lw[3] << 16),
                  lw[4] | (lw[5] << 16), lw[6] | (lw[7] << 16)};
}

// pack (weight, id) -> sortable u64: higher weight first, then smaller id.
__device__ __forceinline__ u64 packwi(float w, int id) {
    return ((u64)__float_as_uint(w) << 32) | (unsigned)(~id);
}

__device__ __forceinline__ void u64ins(u64* ms, int t, u64 v) {
    const int b = t * NTOP;
    if (v <= ms[b + NTOP - 1]) return;
    int p = NTOP - 1;
    while (p > 0 && v > ms[b + p - 1]) { ms[b + p] = ms[b + p - 1]; --p; }
    ms[b + p] = v;
}

// ---------- depth-2 scorer macros (r11/r17 core: no spill at wave granularity) ----------
#define LOADC_CORE(NN, S)                                                    \
    { int nn_ = (NN);                                                        \
      if (nn_ < NCHS) {                                                      \
          int k0_ = nn_ * 16 + khalf * 8;                                    \
          e0[S] = (k0_ + 4 <= EMBD) ? *(const f32x4*)(ebase + k0_) : zf4;    \
          e1[S] = (k0_ + 8 <= EMBD) ? *(const f32x4*)(ebase + k0_ + 4) : zf4;\
          _Pragma("unroll")                                                  \
          for (int t_ = 0; t_ < 4; ++t_) {                                   \
              long fo_ = ((long)(nn_ * 4 + t_) * 64 + lane) * 8;             \
              wh[S][t_] = *(const u32x4*)&wfH[fo_];                          \
              wl[S][t_] = *(const u32x4*)&wfL[fo_];                          \
          } } }

#define COMP_CORE(CC, S)                                                     \
    { if ((CC) < NCHS) {                                                     \
          union { bf16x8 v; u32x4 u; } eh_, el_;                             \
          split8(e0[S], e1[S], &eh_.u, &el_.u);                              \
          _Pragma("unroll")                                                  \
          for (int t_ = 0; t_ < 4; ++t_) {                                   \
              union { bf16x8 v; u32x4 u; } bh_, bl_;                         \
              bh_.u = wh[S][t_]; bl_.u = wl[S][t_];                          \
              acc[t_] = __builtin_amdgcn_mfma_f32_32x32x16_bf16(eh_.v, bh_.v, acc[t_], 0, 0, 0); \
              acc[t_] = __builtin_amdgcn_mfma_f32_32x32x16_bf16(eh_.v, bl_.v, acc[t_], 0, 0, 0); \
              acc[t_] = __builtin_amdgcn_mfma_f32_32x32x16_bf16(el_.v, bh_.v, acc[t_], 0, 0, 0); \
          } } }

#define SCORE_BATCH_BODY                                                     \
    {                                                                        \
        f32x16 acc[4];                                                       \
        _Pragma("unroll")                                                    \
        for (int t_ = 0; t_ < 4; ++t_)                                       \
            _Pragma("unroll")                                                \
            for (int r_ = 0; r_ < 16; ++r_) acc[t_][r_] = 0.f;               \
        f32x4 e0[2], e1[2];                                                  \
        u32x4 wh[2][4], wl[2][4];                                            \
        const f32x4 zf4 = (f32x4){0.f, 0.f, 0.f, 0.f};                       \
        LOADC_CORE(0, 0) LOADC_CORE(1, 1)                                    \
        for (int g_ = 0; g_ < 10; ++g_) {                                    \
            const int c_ = g_ * 2;                                           \
            COMP_CORE(c_ + 0, 0) LOADC_CORE(c_ + 2, 0)                       \
            COMP_CORE(c_ + 1, 1) LOADC_CORE(c_ + 3, 1)                       \
        }                                                                    \
        float pr[16];                                                        \
        _Pragma("unroll")                                                    \
        for (int r_ = 0; r_ < 16; ++r_) {                                    \
            float s_ = 0.f;                                                  \
            _Pragma("unroll")                                                \
            for (int t_ = 0; t_ < 4; ++t_) {                                 \
                float h_ = fmaxf(acc[t_][r_] + qv[t_], 0.f);                 \
                s_ += h_ * w2v[t_];                                          \
            }                                                                \
            s_ += __shfl_xor(s_, 1); s_ += __shfl_xor(s_, 2);                \
            s_ += __shfl_xor(s_, 4); s_ += __shfl_xor(s_, 8);                \
            s_ += __shfl_xor(s_, 16);                                        \
            pr[r_] = s_;                                                     \
        }                                                                    \
        if (lrow == 0) {                                                     \
            _Pragma("unroll")                                                \
            for (int r_ = 0; r_ < 16; ++r_)                                  \
                pv[(r_ & 3) + 8 * (r_ >> 2) + 4 * khalf] = pr[r_];           \
        }                                                                    \
        asm volatile("s_waitcnt lgkmcnt(0)" ::: "memory");                   \
        __builtin_amdgcn_sched_barrier(0);                                   \
    }

// ---------- k_zero: counts + hacc ----------
__global__ __launch_bounds__(256) void k_zero(int* __restrict__ p) {
    const int NI = (WS_HACC + 512) / 4;   // counts + hacc
    for (int i = blockIdx.x * 256 + threadIdx.x; i < NI; i += gridDim.x * 256)
        p[i] = 0;
}

// ---------- k_histplus: histogram | qctx+qcb | W fragment table ----------
__global__ __launch_bounds__(256) void k_histplus(
        const int* __restrict__ fdocs, int n, int* __restrict__ counts,
        const int* __restrict__ qterms, const float* __restrict__ emb,
        const float* __restrict__ sW1, const float* __restrict__ sb1,
        float* __restrict__ qctx, float* __restrict__ qcb,
        unsigned short* __restrict__ wfH, unsigned short* __restrict__ wfL) {
    const int b = blockIdx.x;
    const int t = threadIdx.x;
    if (b < HB) {
        for (int i = b * 256 + t; i < n; i += HB * 256)
            atomicAdd(&counts[fdocs[i]], 1);
        return;
    }
    if (b == HB) {                       // qctx + qcb
        __shared__ int qid[NQ];
        __shared__ float qc[EMBD];
        if (t < NQ) qid[t] = qterms[t];
        __syncthreads();
        for (int i = t; i < EMBD; i += 256) {
            float s = 0.f;
            for (int q = 0; q < NQ; ++q) s += emb[(long)qid[q] * EMBD + i];
            float v = s * (1.0f / NQ);
            qc[i] = v; qctx[i] = v;
        }
        __syncthreads();
        int col = t >> 1, half = t & 1;
        float a = 0.f;
        int k0 = half * 150;
        for (int k = k0; k < k0 + 150; ++k)
            a += qc[k] * sW1[(long)(EMBD + k) * HID + col];
        a += __shfl_xor(a, 1);
        if (half == 0) qcb[col] = a + sb1[col];
        return;
    }
    // W fragment table: 5120 builders over 20 blocks
    int i = (b - HB - 1) * 256 + t;
    int c = i >> 8;
    int rest = i & 255;
    int tile = rest >> 6;
    int l = rest & 63;
    int col = tile * 32 + (l & 31);
    int kbase = c * 16 + (l >> 5) * 8;
    unsigned int hw[8], lw[8];
#pragma unroll
    for (int j = 0; j < 8; ++j) {
        int k = kbase + j;
        unsigned int hi = 0, lo = 0;
        if (k < EMBD) {
            float f = sW1[(long)k * HID + col];
            unsigned int u = __float_as_uint(f);
            hi = u >> 16;
            float r = __uint_as_float(u & 0xffff0000u);
            lo = __float_as_uint(f - r) >> 16;
        }
        hw[j] = hi; lw[j] = lo;
    }
    long fo = ((long)(c * 4 + tile) * 64 + l) * 8;
    *(u32x4*)&wfH[fo] = (u32x4){hw[0] | (hw[1] << 16), hw[2] | (hw[3] << 16),
                                hw[4] | (hw[5] << 16), hw[6] | (hw[7] << 16)};
    *(u32x4*)&wfL[fo] = (u32x4){lw[0] | (lw[1] << 16), lw[2] | (lw[3] << 16),
                                lw[4] | (lw[5] << 16), lw[6] | (lw[7] << 16)};
}

// ---------- k_scoreAC: 98-row range compact + batch MFMA score + wave top-10 (packed) ----------
__global__ __launch_bounds__(64) void k_scoreAC(
        const float* __restrict__ emb,
        const unsigned short* __restrict__ wfH,
        const unsigned short* __restrict__ wfL,
        const float* __restrict__ qcb,
        const float* __restrict__ sW2,
        const float* __restrict__ sb2,
        const int* __restrict__ counts,
        u64* __restrict__ tpack) {
    const int lane = threadIdx.x;
    const int blk = blockIdx.x;
    const int lrow = lane & 31;
    const int khalf = lane >> 5;
    const int base0 = blk * RANGE;

    __shared__ int   cl_id[RANGE_PAD];
    __shared__ int   cl_cnt[RANGE_PAD];
    __shared__ float allw[RANGE_PAD];
    __shared__ float pv[32];

    // uniform 2-iteration ballot compaction (r16 lesson: all lanes, all iters)
    int ncl = 0;
#pragma unroll
    for (int it = 0; it < 2; ++it) {
        int i = it * 64 + lane;
        int v = base0 + i;
        int c = (i < RANGE && v < VOCABN) ? counts[v] : 0;
        bool pred = (c >= CMIN);
        u64 m = __ballot(pred);
        if (pred) {
            int pos = ncl + __popcll(m & ((1ull << lane) - 1ull));
            cl_id[pos] = v; cl_cnt[pos] = c;
        }
        ncl += __popcll(m);
    }
    __syncthreads();

    if (ncl == 0) {
        if (lane < NTOP) tpack[blk * NTOP + lane] = 0;
        return;
    }

    float qv[4], w2v[4];
#pragma unroll
    for (int t = 0; t < 4; ++t) {
        qv[t] = qcb[t * 32 + lrow];
        w2v[t] = sW2[t * 32 + lrow];
    }
    const float b2 = sb2[0];

    const int nb = (ncl + 31) >> 5;    // <= 4
    for (int bt = 0; bt < nb; ++bt) {
        int idx = bt * 32 + lrow;
        bool val = idx < ncl;
        int vrow = val ? cl_id[idx] : cl_id[0];
        const float* ebase = emb + (long)vrow * EMBD;

        SCORE_BATCH_BODY

        float w = -1.f;
        if (val) w = (float)cl_cnt[idx] / (1.f + expf(-(pv[lrow] + b2)));
        allw[bt * 32 + lrow] = w;
        __syncthreads();
    }

    // wave top-10 with knockout (strided scan; ncl wave-uniform)
    for (int r = 0; r < NTOP; ++r) {
        float bw = -1.f; int bid = 0x7fffffff; int bslot = -1;
        for (int i = lane; i < ncl; i += 64) {
            float w = allw[i]; int id = cl_id[i];
            if (w > bw || (w == bw && id < bid)) { bw = w; bid = id; bslot = i; }
        }
#pragma unroll
        for (int mm = 1; mm < 64; mm <<= 1) {
            float ow = __shfl_xor(bw, mm);
            int oid = __shfl_xor(bid, mm);
            int osl = __shfl_xor(bslot, mm);
            if (ow > bw || (ow == bw && oid < bid)) { bw = ow; bid = oid; bslot = osl; }
        }
        if (lane == 0 && bslot >= 0) allw[bslot] = -2.f;
        if (lane == r) tpack[blk * NTOP + r] = (bw > 0.f) ? packwi(bw, bid) : 0;
        __syncthreads();
    }
}

// ---------- k_mh: redundant merge -> (h-partials | output writes) ----------
__global__ __launch_bounds__(256) void k_mh(
        const u64* __restrict__ tpack,
        const float* __restrict__ qctx, const float* __restrict__ emb,
        const unsigned short* __restrict__ wfH, const unsigned short* __restrict__ wfL,
        const float* __restrict__ qcb, const float* __restrict__ sW2,
        const float* __restrict__ sb2, const int* __restrict__ counts,
        const float* __restrict__ eW1, const float* __restrict__ eb2,
        float* __restrict__ hacc, float* __restrict__ out) {
    __shared__ u64 ms[256 * NTOP];
    __shared__ int tid_s[NTOP];
    __shared__ float tw_s[NTOP];
    __shared__ float feat_s[KSLC + 7];
    __shared__ float pvs[4][32];
    const int t = threadIdx.x;
    const int b = blockIdx.x;

    // merge scan of packed candidates (80 KB, parallel across all blocks)
#pragma unroll
    for (int n = 0; n < NTOP; ++n) ms[t * NTOP + n] = 0;
    for (int i = t; i < NBLK_AC * NTOP; i += 256) u64ins(ms, t, tpack[i]);
    for (int s = 128; s > 0; s >>= 1) {
        __syncthreads();
        if (t < s) {
            const int ta = t * NTOP, tb = (t + s) * NTOP;
            u64 ov[NTOP]; int i = 0, j = 0;
#pragma unroll
            for (int n = 0; n < NTOP; ++n) {
                u64 va = ms[ta + i], vb = ms[tb + j];
                if (va > vb) { ov[n] = va; ++i; } else { ov[n] = vb; ++j; }
            }
#pragma unroll
            for (int n = 0; n < NTOP; ++n) ms[ta + n] = ov[n];
        }
    }
    __syncthreads();

    // exactness flag: excluded rows (count<=2) have weight < 2
    bool flag = (ms[NTOP - 1] != 0) &&
                (__uint_as_float((unsigned)(ms[NTOP - 1] >> 32)) >= 2.0f);

    if (!flag) {
        // never in practice: block-local dense rescore of the full vocab
        __syncthreads();
#pragma unroll
        for (int n = 0; n < NTOP; ++n) ms[t * NTOP + n] = 0;
        const int lane = t & 63;
        const int wave = t >> 6;
        const int lrow = lane & 31;
        const int khalf = lane >> 5;
        float qv[4], w2v[4];
#pragma unroll
        for (int tt = 0; tt < 4; ++tt) {
            qv[tt] = qcb[tt * 32 + lrow];
            w2v[tt] = sW2[tt * 32 + lrow];
        }
        const float b2 = sb2[0];
        const int ntile = (VOCABN + 31) / 32;
        for (int tile = wave; tile < ntile; tile += 4) {
            const int base = tile * 32;
            int rc = base + lrow; if (rc > VOCABN - 1) rc = VOCABN - 1;
            const float* ebase = emb + (long)rc * EMBD;
            float* pv = pvs[wave];
            SCORE_BATCH_BODY
            int gidx = base + lrow;
            if (khalf == 0 && gidx < VOCABN) {
                float w = (float)counts[gidx] / (1.f + expf(-(pv[lrow] + b2)));
                u64ins(ms, t, packwi(w, gidx));
            }
        }
        for (int s = 128; s > 0; s >>= 1) {
            __syncthreads();
            if (t < s) {
                const int ta = t * NTOP, tb = (t + s) * NTOP;
                u64 ov[NTOP]; int i = 0, j = 0;
#pragma unroll
                for (int n = 0; n < NTOP; ++n) {
                    u64 va = ms[ta + i], vb = ms[tb + j];
                    if (va > vb) { ov[n] = va; ++i; } else { ov[n] = vb; ++j; }
                }
#pragma unroll
                for (int n = 0; n < NTOP; ++n) ms[ta + n] = ov[n];
            }
        }
        __syncthreads();
    }

    if (t < NTOP) {
        u64 v = ms[t];
        int id = (int)(~(unsigned)v);
        if (id < 0 || id >= VOCABN) id = 0;           // sentinel clamp
        tid_s[t] = id;
        tw_s[t] = (v == 0) ? -1.f : __uint_as_float((unsigned)(v >> 32));
    }
    __syncthreads();

    if (b == 16) {     // output writer
        if (t < NTOP) {
            out[EMBD + t] = (float)tid_s[t];
            out[EMBD + NTOP + t] = tw_s[t];
        }
        for (int i = t; i < EMBD; i += 256) out[i] = eb2[i];
        return;
    }

    // h-partial over k-slice [b*KSLC, min(900, b*KSLC+KSLC))
    const int kstart = b * KSLC;
    const int kend = (kstart + KSLC < 3 * EMBD) ? kstart + KSLC : 3 * EMBD;
    const int klen = kend - kstart;
    for (int kk = t; kk < klen; kk += 256) {
        int k = kstart + kk;
        float f;
        if (k < EMBD) f = qctx[k];
        else {
            int d = (k < 2 * EMBD) ? k - EMBD : k - 2 * EMBD;
            float em_d = 0.f;
#pragma unroll
            for (int n = 0; n < NTOP; ++n) em_d += emb[(long)tid_s[n] * EMBD + d];
            em_d *= (1.0f / NTOP);
            f = (k < 2 * EMBD) ? em_d : qctx[d] * em_d;
        }
        feat_s[kk] = f;
    }
    __syncthreads();

    const int col = t & 127;
    const int kg = t >> 7;
    float a = 0.f;
    for (int k = kstart + kg; k < kend; k += 2)
        a += feat_s[k - kstart] * eW1[(long)k * HID + col];
    atomicAdd(&hacc[col], a);
}

// ---------- k_out: out[i] += sum_j relu(hacc+eb1)[j] * eW2[j][i] ----------
__global__ __launch_bounds__(256) void k_out(
        const float* __restrict__ hacc, const float* __restrict__ eb1,
        const float* __restrict__ eW2, float* __restrict__ out) {
    const int b = blockIdx.x;
    const int t = threadIdx.x;
    __shared__ float hj[8];
    if (t < 8) {
        int j = b * 8 + t;
        hj[t] = fmaxf(hacc[j] + eb1[j], 0.f);
    }
    __syncthreads();
    for (int i = t; i < EMBD; i += 256) {
        float a = 0.f;
#pragma unroll
        for (int jj = 0; jj < 8; ++jj)
            a += hj[jj] * eW2[(long)(b * 8 + jj) * EMBD + i];
        atomicAdd(&out[i], a);
    }
}

extern "C" void kernel_launch(void* const* d_in, const int* in_sizes, int n_in,
                              void* d_out, int out_size, void* d_ws, size_t ws_size,
                              hipStream_t stream) {
    const int* qterms  = (const int*)d_in[0];
    const int* fdocs   = (const int*)d_in[1];
    const float* emb   = (const float*)d_in[3];
    const float* sW1   = (const float*)d_in[4];
    const float* sb1   = (const float*)d_in[5];
    const float* sW2   = (const float*)d_in[6];
    const float* sb2   = (const float*)d_in[7];
    const float* eW1   = (const float*)d_in[8];
    const float* eb1   = (const float*)d_in[9];
    const float* eW2   = (const float*)d_in[10];
    const float* eb2   = (const float*)d_in[11];
    char* ws = (char*)d_ws;
    float* out = (float*)d_out;

    int*   counts = (int*)ws;
    float* hacc   = (float*)(ws + WS_HACC);
    float* qctx   = (float*)(ws + WS_QCTX);
    float* qcb    = (float*)(ws + WS_QCB);
    unsigned short* wfH = (unsigned short*)(ws + WS_WFH);
    unsigned short* wfL = (unsigned short*)(ws + WS_WFL);
    u64*   tpack  = (u64*)(ws + WS_TPACK);

    int nflat = in_sizes[1];

    k_zero<<<512, 256, 0, stream>>>(counts);
    k_histplus<<<HB + 1 + 20, 256, 0, stream>>>(fdocs, nflat, counts, qterms, emb,
                                                sW1, sb1, qctx, qcb, wfH, wfL);
    k_scoreAC<<<NBLK_AC, 64, 0, stream>>>(emb, wfH, wfL, qcb, sW2, sb2, counts, tpack);
    k_mh<<<17, 256, 0, stream>>>(tpack, qctx, emb, wfH, wfL, qcb, sW2, sb2,
                                 counts, eW1, eb2, hacc, out);
    k_out<<<16, 256, 0, stream>>>(hacc, eb1, eW2, out);
}